// Round 17
// baseline (1896.977 us; speedup 1.0000x reference)
//
#include <hip/hip_runtime.h>
#include <hip/hip_bf16.h>
#include <stdint.h>

#define Bb 32
#define Tt 512
#define Dd 1024
#define Hh 1024
#define Cc 1000
#define Mm (Bb*Tt)
#define SENT 0x7F7F7F7Fu

typedef float f32x4 __attribute__((ext_vector_type(4)));
typedef short bf16x8 __attribute__((ext_vector_type(8)));

#define MFMA16(a,b,c) __builtin_amdgcn_mfma_f32_16x16x32_bf16(a,b,c,0,0,0)

static __device__ __forceinline__ unsigned short f2b(float f){
  __hip_bfloat16 h = __float2bfloat16(f);
  union { __hip_bfloat16 h; unsigned short u; } cv; cv.h = h; return cv.u;
}
static __device__ __forceinline__ float b2f(unsigned short u){
  union { unsigned int i; float f; } cv; cv.i = ((unsigned int)u) << 16; return cv.f;
}

static __device__ __forceinline__ void async16(const ushort* g, ushort* l){
  __builtin_amdgcn_global_load_lds((const __attribute__((address_space(1))) unsigned int*)g,
                                   (__attribute__((address_space(3))) unsigned int*)l,
                                   16, 0, 0);
}

// h exchange: FAST (same-XCD) = sc1 (bypass L1, XCD-L2 coherent); safe = sc0 sc1 (L3).
template<int FAST>
static __device__ __forceinline__ bf16x8 h_load(const ushort* p){
  bf16x8 r;
  if constexpr (FAST)
    asm volatile("global_load_dwordx4 %0, %1, off sc1" : "=v"(r) : "v"(p) : "memory");
  else
    asm volatile("global_load_dwordx4 %0, %1, off sc0 sc1" : "=v"(r) : "v"(p) : "memory");
  return r;
}
template<int FAST>
static __device__ __forceinline__ void h_store(ushort* p, unsigned int v){
  if constexpr (FAST)
    asm volatile("global_store_dword %0, %1, off sc1" :: "v"(p), "v"(v) : "memory");
  else
    asm volatile("global_store_dword %0, %1, off sc0 sc1" :: "v"(p), "v"(v) : "memory");
}

static __device__ __forceinline__ int load4sys(const int* p){
  int v;
  asm volatile("global_load_dword %0, %1, off sc0 sc1" : "=v"(v) : "v"(p) : "memory");
  asm volatile("s_waitcnt vmcnt(0)" ::: "memory");
  return v;
}
static __device__ __forceinline__ void store4sys(int* p, int v){
  asm volatile("global_store_dword %0, %1, off sc0 sc1" :: "v"(p), "v"(v) : "memory");
}

// ---------------- conversion kernels ----------------

__global__ void cvt_bf16(const float* __restrict__ in, ushort* __restrict__ out, int n4){
  int i = blockIdx.x*256 + threadIdx.x;
  if (i < n4){
    const float4 v = ((const float4*)in)[i];
    ushort4 o;
    o.x = f2b(v.x); o.y = f2b(v.y); o.z = f2b(v.z); o.w = f2b(v.w);
    ((ushort4*)out)[i] = o;
  }
}

// all weight conversions + W2 pad + b2 pad in ONE launch
static __device__ __forceinline__ void cvt4(const float* s, ushort* d){
  const float4 v = *(const float4*)s;
  ushort4 o; o.x=f2b(v.x); o.y=f2b(v.y); o.z=f2b(v.z); o.w=f2b(v.w);
  *(ushort4*)d = o;
}
__global__ void prep_weights(const float* __restrict__ Wp,  const float* __restrict__ Wih,
                             const float* __restrict__ Whh, const float* __restrict__ W1,
                             const float* __restrict__ W2,  const float* __restrict__ b2,
                             ushort* __restrict__ wpb, ushort* __restrict__ wihb,
                             ushort* __restrict__ whhb, ushort* __restrict__ w1b,
                             ushort* __restrict__ w2b, float* __restrict__ b2p)
{
  const long i = (long)blockIdx.x*256 + threadIdx.x;   // quad index
  const long Q0 = 262144;            // Wp   1M floats
  const long Q1 = Q0 + 786432;       // Wih  3M
  const long Q2 = Q1 + 786432;       // Whh  3M
  const long Q3 = Q2 + 262144;       // W1   1M
  const long Q4 = Q3 + 262144;       // W2 pad (1024x1024 out)
  const long Q5 = Q4 + 256;          // b2p 1024 floats
  if (i < Q0){            cvt4(Wp  + i*4,      wpb  + i*4); }
  else if (i < Q1){ long j=i-Q0; cvt4(Wih + j*4, wihb + j*4); }
  else if (i < Q2){ long j=i-Q1; cvt4(Whh + j*4, whhb + j*4); }
  else if (i < Q3){ long j=i-Q2; cvt4(W1  + j*4, w1b  + j*4); }
  else if (i < Q4){
    long j=i-Q3; int r = (int)(j>>8), c4 = (int)(j&255)*4;
    ushort4 o;
    if (r < Cc){
      const float4 v = *(const float4*)&W2[(size_t)r*1024 + c4];
      o.x=f2b(v.x); o.y=f2b(v.y); o.z=f2b(v.z); o.w=f2b(v.w);
    } else { o.x=0; o.y=0; o.z=0; o.w=0; }
    *(ushort4*)&w2b[(size_t)r*1024 + c4] = o;
  } else if (i < Q5){
    long j=i-Q4; int c4=(int)j*4;
#pragma unroll
    for (int k=0;k<4;k++){ int c=c4+k; b2p[c] = (c<Cc)? b2[c] : 0.f; }
  }
}

// ---------------- generic bf16 MFMA GEMM (m97 structure + XCD swizzle) ----------------
// PERM_A / PERM_C: buffer stored row-permuted [(m&511)*32 + (m>>9)] = [t*32+b]

template<int RELU, int OUT_BF16, int PERM_A, int PERM_C>
__global__ __launch_bounds__(256) void gemm_bt(
    const ushort* __restrict__ A, const ushort* __restrict__ Bm,
    const float* __restrict__ bias, void* __restrict__ Cp,
    int M, int N, int K, int ldc, int nout)
{
  __shared__ ushort As[128*32];
  __shared__ ushort Bs[128*32];
  const int tid  = threadIdx.x;
  const int lane = tid & 63;
  const int wave = tid >> 6;
  const int wr = wave >> 1, wc = wave & 1;
  const int r0 = lane & 15, kg = lane >> 4;

  const int nwg = gridDim.x * gridDim.y;
  const int lin = blockIdx.y * gridDim.x + blockIdx.x;
  const int cpx = nwg >> 3;
  const int swz = (lin & 7) * cpx + (lin >> 3);
  const int bx = swz % gridDim.x, by = swz / gridDim.x;

  const int m0 = bx*128, n0 = by*128;

  const int lrA0 = m0 + (tid>>2);
  const int lrA1 = lrA0 + 64;
  const size_t prA0 = PERM_A ? (size_t)((lrA0 & 511)*32 + (lrA0 >> 9)) : (size_t)lrA0;
  const size_t prA1 = PERM_A ? (size_t)((lrA1 & 511)*32 + (lrA1 >> 9)) : (size_t)lrA1;
  const ushort* aG0 = A  + prA0*K + (tid&3)*8;
  const ushort* aG1 = A  + prA1*K + (tid&3)*8;
  const ushort* bG  = Bm + (size_t)(n0 + (tid>>2))*K + (tid&3)*8;
  ushort* aL = As + tid*8;
  ushort* bL = Bs + tid*8;
  const size_t rstep = (size_t)64*K;

  f32x4 acc[4][4] = {};

  for (int kt = 0; kt < K; kt += 32){
    __syncthreads();
    async16(aG0 + kt, aL);
    async16(aG1 + kt, aL + 2048);
    async16(bG + kt,         bL);
    async16(bG + kt + rstep, bL + 2048);
    __syncthreads();
    bf16x8 af[4], bf_[4];
#pragma unroll
    for (int i=0;i<4;i++) af[i]  = *(const bf16x8*)&As[(wr*64 + i*16 + r0)*32 + kg*8];
#pragma unroll
    for (int j=0;j<4;j++) bf_[j] = *(const bf16x8*)&Bs[(wc*64 + j*16 + r0)*32 + kg*8];
#pragma unroll
    for (int i=0;i<4;i++)
#pragma unroll
      for (int j=0;j<4;j++)
        acc[i][j] = MFMA16(af[i], bf_[j], acc[i][j]);
  }

  const int rowb = m0 + wr*64 + kg*4;
  const int colb = n0 + wc*64 + r0;
#pragma unroll
  for (int i=0;i<4;i++){
#pragma unroll
    for (int j=0;j<4;j++){
      const int c = colb + j*16;
      if (c >= nout) continue;
      const float bv = bias ? bias[c] : 0.f;
#pragma unroll
      for (int q=0;q<4;q++){
        const int r = rowb + i*16 + q;
        const size_t pr = PERM_C ? (size_t)((r & 511)*32 + (r >> 9)) : (size_t)r;
        float v = acc[i][j][q] + bv;
        if (RELU) v = fmaxf(v, 0.f);
        if (OUT_BF16) ((ushort*)Cp)[pr*ldc + c] = f2b(v);
        else          ((float* )Cp)[pr*ldc + c] = v;
      }
    }
  }
}

// ---------------- persistent GRU scan + fused out1 (wide epilogues) ----------------
// R17 = R16 + watertight gx double-buffer swap: the xr<-xrN register copy is
// preceded by an asm that BINDS the waitcnt to the registers
// (s_waitcnt vmcnt(0) with "+v"(xrN..)), so the mov can never read a
// register whose async load is still in flight (R16's replay race).

#define REDN  4656
#define REDN2 1584

template<int FAST>
static __device__ __forceinline__ void scan_body(
    const int g, const int m, const int tid,
    const ushort* __restrict__ Whh, const float* __restrict__ bhh,
    const ushort* __restrict__ W1b, const float* __restrict__ b1,
    const ushort* __restrict__ gxT, ushort* __restrict__ hsAll,
    ushort* __restrict__ o1, float* __restrict__ red, float* __restrict__ red2)
{
  const int wave = tid >> 6;
  const int lane = tid & 63;
  const int r0 = lane & 15, kg = lane >> 4;
  const int kbase = wave*128 + kg*8;

  bf16x8 wb[6][4];
#pragma unroll
  for (int n=0;n<6;n++){
    const ushort* wr_ = Whh + ((size_t)((n>>1)*1024 + m*32 + (n&1)*16 + r0))*1024 + kbase;
#pragma unroll
    for (int ks=0;ks<4;ks++)
      wb[n][ks] = *(const bf16x8*)(wr_ + ks*32);
  }
  bf16x8 w1f[2][4];
#pragma unroll
  for (int n2=0;n2<2;n2++){
    const ushort* wr_ = W1b + ((size_t)(m*32 + n2*16 + r0))*1024 + kbase;
#pragma unroll
    for (int ks=0;ks<4;ks++)
      w1f[n2][ks] = *(const bf16x8*)(wr_ + ks*32);
  }

  // gate epilogue role (waves 0-1): batch eb (0..3), unit u (0..31)
  const int eb = (tid >> 5) & 3;
  const int u  = tid & 31;
  const int jg = m*32 + u;
  float brg=0, bzg=0, bng=0;
  if (tid < 128){
    brg = bhh[jg]; bzg = bhh[1024+jg]; bng = bhh[2048+jg];
  }
  // out1 epilogue role (waves 2-3): batch eb3, col u3
  const int t3  = tid & 127;
  const int eb3 = t3 >> 5;
  const int u3  = t3 & 31;
  const int jg3 = m*32 + u3;
  float b1v = 0.f;
  if (tid >= 128 && tid < 256) b1v = b1[jg3];

  float hold = 0.f;

  // gx register double-buffer (waves 0-1; pair threads load the shared dword)
  unsigned xr=0, xz=0, xn=0, xrN=0, xzN=0, xnN=0;
  const int jgd = jg & ~1;
  if (tid < 128){
    const ushort* gb = gxT + (size_t)(g*4 + eb)*3072 + jgd;
    asm volatile("global_load_dword %0, %1, off" : "=v"(xr) : "v"(gb));
    asm volatile("global_load_dword %0, %1, off" : "=v"(xz) : "v"(gb + 1024));
    asm volatile("global_load_dword %0, %1, off" : "=v"(xn) : "v"(gb + 2048));
  }

  bf16x8 ha[4], haP[4];

  for (int t = 0; t <= Tt+1; ++t){
    const int buf = t & 1;
    const int polled = (t <= Tt);

    const ushort* aB = hsAll + (size_t)(t*32 + g*4 + (r0 & 3))*1024 + kbase;
    if (polled){
#pragma unroll
      for (int ks=0;ks<4;ks++) ha[ks] = h_load<FAST>(aB + ks*32);
    }

    // out1 MFMA on haP (hs row t-2), inside the poll RTT shadow
    if (t >= 2){
      f32x4 acc2[2] = {};
#pragma unroll
      for (int ks=0;ks<4;ks++)
#pragma unroll
        for (int n2=0;n2<2;n2++)
          acc2[n2] = MFMA16(haP[ks], w1f[n2][ks], acc2[n2]);
      if (kg == 0){
        float* rb2 = red2 + buf*REDN2;
#pragma unroll
        for (int n2=0;n2<2;n2++)
#pragma unroll
          for (int q=0;q<4;q++)
            rb2[(q*33 + n2*16 + r0)*12 + wave] = acc2[n2][q];
      }
    }

    if (polled){
      int again;
      for(;;){
        asm volatile("s_waitcnt vmcnt(0)" ::: "memory");
        __builtin_amdgcn_sched_barrier(0);
        unsigned sent = 0;
#pragma unroll
        for (int ks=0;ks<4;ks++){
          union { bf16x8 v; unsigned u[4]; } A; A.v = ha[ks];
#pragma unroll
          for (int q=0;q<4;q++) sent |= (A.u[q] == SENT);
        }
        again = __any((int)sent);
        if (!again) break;
#pragma unroll
        for (int ks=0;ks<4;ks++) ha[ks] = h_load<FAST>(aB + ks*32);
      }
    }

    // gx(t+1) prefetch (async; drained by the bound waitcnt in the epilogue)
    if (tid < 128 && t+1 < Tt){
      const ushort* gb = gxT + (size_t)((t+1)*32 + g*4 + eb)*3072 + jgd;
      asm volatile("global_load_dword %0, %1, off" : "=v"(xrN) : "v"(gb));
      asm volatile("global_load_dword %0, %1, off" : "=v"(xzN) : "v"(gb + 1024));
      asm volatile("global_load_dword %0, %1, off" : "=v"(xnN) : "v"(gb + 2048));
    }

    if (t < Tt){
      f32x4 acc[6] = {};
#pragma unroll
      for (int ks=0;ks<4;ks++)
#pragma unroll
        for (int n=0;n<6;n++)
          acc[n] = MFMA16(ha[ks], wb[n][ks], acc[n]);
      if (kg == 0){
        float* rb = red + buf*REDN;
#pragma unroll
        for (int n=0;n<6;n++)
#pragma unroll
          for (int q=0;q<4;q++)
            rb[(q*97 + n*16 + r0)*12 + wave] = acc[n][q];
      }
    }

    __syncthreads();

    // waves 0-1: gate epilogue (one unit per thread) + paired dword publish
    if (t < Tt && tid < 128){
      const float* rb = red + buf*REDN;
      float sr, sz, sn;
      {
        const int slot = eb*97 + u;
        const float4 a  = *(const float4*)&rb[slot*12];
        const float4 b4 = *(const float4*)&rb[slot*12 + 4];
        sr = (a.x + a.y) + (a.z + a.w) + (b4.x + b4.y) + (b4.z + b4.w);
      }
      {
        const int slot = eb*97 + 32 + u;
        const float4 a  = *(const float4*)&rb[slot*12];
        const float4 b4 = *(const float4*)&rb[slot*12 + 4];
        sz = (a.x + a.y) + (a.z + a.w) + (b4.x + b4.y) + (b4.z + b4.w);
      }
      {
        const int slot = eb*97 + 64 + u;
        const float4 a  = *(const float4*)&rb[slot*12];
        const float4 b4 = *(const float4*)&rb[slot*12 + 4];
        sn = (a.x + a.y) + (a.z + a.w) + (b4.x + b4.y) + (b4.z + b4.w);
      }
      const ushort xh = (ushort)((u & 1) ? (xr >> 16) : (xr & 0xffff));
      const ushort zh = (ushort)((u & 1) ? (xz >> 16) : (xz & 0xffff));
      const ushort nh = (ushort)((u & 1) ? (xn >> 16) : (xn & 0xffff));
      const float r = 1.f/(1.f + __expf(-(b2f(xh) + sr + brg)));
      const float z = 1.f/(1.f + __expf(-(b2f(zh) + sz + bzg)));
      const float a = b2f(nh) + r*(sn + bng);
      const float e = __expf(-2.f*a);
      const float n = (1.f - e)/(1.f + e);
      const float hnew = (1.f - z)*n + z*hold;
      hold = hnew;
      const unsigned hu = (unsigned)f2b(hnew);
      const unsigned po = (unsigned)__shfl_xor((int)hu, 1);
      // watertight double-buffer swap: waitcnt BOUND to the prefetch regs,
      // so xr<-xrN cannot read an in-flight register (R16 replay race).
      // Placed before h_store so the store ack stays off-chain.
      asm volatile("s_waitcnt vmcnt(0)" : "+v"(xrN), "+v"(xzN), "+v"(xnN) :: "memory");
      __builtin_amdgcn_sched_barrier(0);
      xr = xrN; xz = xzN; xn = xnN;
      if (!(u & 1)){
        const unsigned packed = hu | (po << 16);
        h_store<FAST>(hsAll + (size_t)((t+1)*32 + g*4 + eb)*1024 + jg, packed);
      }
    }

    // waves 2-3: out1 epilogue for hs row (t-2) (one col per thread)
    if (t >= 2 && tid >= 128 && tid < 256){
      const float* rb2 = red2 + buf*REDN2;
      const int slot = eb3*33 + u3;
      const float4 a  = *(const float4*)&rb2[slot*12];
      const float4 b4 = *(const float4*)&rb2[slot*12 + 4];
      const float s0 = (a.x + a.y) + (a.z + a.w) + (b4.x + b4.y) + (b4.z + b4.w);
      const float o0 = fmaxf(s0 + b1v, 0.f);
      const unsigned ou = (unsigned)f2b(o0);
      const unsigned po = (unsigned)__shfl_xor((int)ou, 1);
      if (!(u3 & 1)){
        const unsigned packed = ou | (po << 16);
        *(unsigned*)(o1 + (size_t)((t-2)*32 + g*4 + eb3)*1024 + jg3) = packed;
      }
    }

    if (polled){
#pragma unroll
      for (int ks=0;ks<4;ks++) haP[ks] = ha[ks];
    }
  }
}

__global__ __launch_bounds__(512, 1) void gru_scan(
    const ushort* __restrict__ Whh, const float* __restrict__ bhh,
    const ushort* __restrict__ W1b, const float* __restrict__ b1,
    const ushort* __restrict__ gxT,   // [t][b][3H]
    ushort* __restrict__ hsAll,       // [Tt+1][32][1024]; rows 0..31 zeroed, rest SENT
    ushort* __restrict__ o1,          // [t][b][1024]
    int* __restrict__ xccTab)
{
  __shared__ float red[2*REDN];
  __shared__ float red2[2*REDN2];
  __shared__ int fastFlag;
  const int bid = blockIdx.x;
  const int g = bid & 7, m = bid >> 3;
  const int tid = threadIdx.x;
  int* decTab = xccTab + 256;

  if (tid == 0){
    int myxcc;
    asm volatile("s_getreg_b32 %0, hwreg(HW_REG_XCC_ID)" : "=s"(myxcc));
    store4sys(&xccTab[bid], myxcc);
    if (m == 0){
      int ok = 1;
      long budget = 200000;
      for (int p = 0; p < 32 && ok; ++p){
        int v;
        do {
          v = load4sys(&xccTab[p*8 + g]);
          if (v == -1){ __builtin_amdgcn_s_sleep(1); if (--budget <= 0){ ok = 0; break; } }
        } while (v == -1);
        if (v != myxcc) ok = 0;
      }
      store4sys(&decTab[g], ok);
      fastFlag = ok;
    } else {
      int v;
      do {
        v = load4sys(&decTab[g]);
        if (v == -1) __builtin_amdgcn_s_sleep(1);
      } while (v == -1);
      fastFlag = v;
    }
  }
  __syncthreads();

  if (fastFlag) scan_body<1>(g, m, tid, Whh, bhh, W1b, b1, gxT, hsAll, o1, red, red2);
  else          scan_body<0>(g, m, tid, Whh, bhh, W1b, b1, gxT, hsAll, o1, red, red2);
}

// ---------------- launch ----------------

extern "C" void kernel_launch(void* const* d_in, const int* in_sizes, int n_in,
                              void* d_out, int out_size, void* d_ws, size_t ws_size,
                              hipStream_t stream)
{
  const float* features = (const float*)d_in[0];
  const float* Wp  = (const float*)d_in[1];
  const float* bp  = (const float*)d_in[2];
  const float* Wih = (const float*)d_in[3];
  const float* bih = (const float*)d_in[4];
  const float* Whh = (const float*)d_in[5];
  const float* bhh = (const float*)d_in[6];
  const float* W1  = (const float*)d_in[7];
  const float* b1  = (const float*)d_in[8];
  const float* W2  = (const float*)d_in[9];
  const float* b2  = (const float*)d_in[10];
  float* out = (float*)d_out;

  char* w = (char*)d_ws;
  auto alloc = [&](size_t bytes){ char* p = w; w += (bytes + 255) & ~(size_t)255; return p; };
  ushort* fb    = (ushort*)alloc((size_t)Mm*Dd*2);
  ushort* xb    = (ushort*)alloc((size_t)Mm*Hh*2);
  ushort* gxT   = (ushort*)alloc((size_t)Mm*3*Hh*2);
  ushort* hsAll = (ushort*)alloc((size_t)(Tt+1)*Bb*Hh*2);
  ushort* o1    = (ushort*)alloc((size_t)Mm*Hh*2);
  ushort* wpb   = (ushort*)alloc((size_t)Hh*Dd*2);
  ushort* wihb  = (ushort*)alloc((size_t)3*Hh*Hh*2);
  ushort* whhb  = (ushort*)alloc((size_t)3*Hh*Hh*2);
  ushort* w1b   = (ushort*)alloc((size_t)Hh*Hh*2);
  ushort* w2b   = (ushort*)alloc((size_t)1024*Hh*2);
  float*  b2p   = (float*)alloc(1024*4);
  int*    xccTab= (int*)alloc(264*4);

  hipMemsetAsync(hsAll, 0x7F, (size_t)(Tt+1)*Bb*Hh*2, stream);
  hipMemsetAsync(hsAll, 0x00, (size_t)Bb*Hh*2, stream);
  hipMemsetAsync(xccTab, 0xFF, 264*4, stream);

  // features cvt (big) + all weight prep (one launch)
  hipLaunchKernelGGL(cvt_bf16, dim3((Mm*Dd/4 + 255)/256), dim3(256), 0, stream,
                     features, fb, Mm*Dd/4);
  hipLaunchKernelGGL(prep_weights, dim3(9217), dim3(256), 0, stream,
                     Wp, Wih, Whh, W1, W2, b2, wpb, wihb, whhb, w1b, w2b, b2p);

  // x = relu(features @ Wp^T + bp)
  hipLaunchKernelGGL((gemm_bt<1,1,0,0>), dim3(Mm/128, Hh/128), dim3(256), 0, stream,
                     fb, wpb, bp, (void*)xb, Mm, Hh, Dd, Hh, Hh);
  // gxT[t][b][:] = x @ W_ih^T + b_ih   (row-permuted C write)
  hipLaunchKernelGGL((gemm_bt<0,1,0,1>), dim3(Mm/128, (3*Hh)/128), dim3(256), 0, stream,
                     xb, wihb, bih, (void*)gxT, Mm, 3*Hh, Hh, 3*Hh, 3*Hh);

  // GRU scan + fused out1
  hipLaunchKernelGGL(gru_scan, dim3(256), dim3(512), 0, stream,
                     whhb, bhh, w1b, b1, gxT, hsAll, o1, xccTab);

  // out = out1 @ W2p^T + b2p  (A row-permuted; store only first 1000 cols, fp32)
  hipLaunchKernelGGL((gemm_bt<0,0,1,0>), dim3(Mm/128, 1024/128), dim3(256), 0, stream,
                     o1, w2b, b2p, (void*)out, Mm, 1024, Hh, Cc, Cc);
}